// Round 3
// baseline (452.661 us; speedup 1.0000x reference)
//
#include <hip/hip_runtime.h>
#include <hip/hip_bf16.h>
#include <cstdint>
#include <cstdio>

#define EMB    1024
#define HEADS  16
#define HD     64
#define TSEQ   2048
#define NBATCH 4
#define BT     (NBATCH*TSEQ)   // 8192
#define QKVN   3072            // fused QKV GEMM output width
#define QKLD   2048            // Q,K buffer row stride

// log2(e) / sqrt(2048) — folded into Wq/bq at cast time
#define CSCALE (1.4426950408889634f * 0.022097086912079608f)

typedef __hip_bfloat16 bf16;
typedef __attribute__((ext_vector_type(8))) short short8;   // 8 bf16 (MFMA A/B frag)
typedef __attribute__((ext_vector_type(4))) short short4v;  // 4 bf16 = 8B
typedef __attribute__((ext_vector_type(4))) float f32x4;    // MFMA C/D frag

__device__ __forceinline__ void gload_lds16(const void* g, void* l) {
  __builtin_amdgcn_global_load_lds(
      (const __attribute__((address_space(1))) void*)g,
      (__attribute__((address_space(3))) void*)l,
      16, 0, 0);
}

// ---------------------------------------------------------------------------
// One launch: cast x -> xb, {Wq*CSCALE,Wk,Wv} -> wqkv, Wp -> wpb,
// concat {bq*CSCALE,bk,bv} -> biasqkv (f32).
// ---------------------------------------------------------------------------
__global__ void fused_cast(const float* __restrict__ x, const float* __restrict__ Wq,
                           const float* __restrict__ Wk, const float* __restrict__ Wv,
                           const float* __restrict__ Wp, const float* __restrict__ bq,
                           const float* __restrict__ bk, const float* __restrict__ bv,
                           bf16* __restrict__ xb, bf16* __restrict__ wqkv,
                           bf16* __restrict__ wpb, float* __restrict__ biasqkv) {
  const int blk = blockIdx.x;
  const int i = threadIdx.x * 4;
  if (blk >= 12288) {  // bias concat: 3 blocks x 1024 f32
    const int wsel = blk - 12288;
    const float* bsrc = wsel == 0 ? bq : (wsel == 1 ? bk : bv);
    float4 bv4 = *(const float4*)(bsrc + i);
    if (wsel == 0) { bv4.x *= CSCALE; bv4.y *= CSCALE; bv4.z *= CSCALE; bv4.w *= CSCALE; }
    *(float4*)(biasqkv + wsel * 1024 + i) = bv4;
    return;
  }
  const float* src; bf16* dst; float sc = 1.0f;
  if (blk < 8192)       { src = x  + (size_t)blk * 1024;           dst = xb   + (size_t)blk * 1024; }
  else if (blk < 9216)  { src = Wq + (size_t)(blk - 8192) * 1024;  dst = wqkv + (size_t)(blk - 8192) * 1024; sc = CSCALE; }
  else if (blk < 10240) { src = Wk + (size_t)(blk - 9216) * 1024;  dst = wqkv + ((size_t)1 << 20) + (size_t)(blk - 9216) * 1024; }
  else if (blk < 11264) { src = Wv + (size_t)(blk - 10240) * 1024; dst = wqkv + ((size_t)2 << 20) + (size_t)(blk - 10240) * 1024; }
  else                  { src = Wp + (size_t)(blk - 11264) * 1024; dst = wpb  + (size_t)(blk - 11264) * 1024; }
  float4 v = *(const float4*)(src + i);
  union { short4v v; bf16 b[4]; } u;
  u.b[0] = __float2bfloat16(v.x * sc); u.b[1] = __float2bfloat16(v.y * sc);
  u.b[2] = __float2bfloat16(v.z * sc); u.b[3] = __float2bfloat16(v.w * sc);
  *(short4v*)(dst + i) = u.v;
}

// ---------------------------------------------------------------------------
// C[M,N] = A[M,K] @ B[N,K]^T + bias.  m97 structure (128x128, BK=32,
// global_load_lds w=16, 16x16x32 MFMA, 4 waves 2x2).
// MODE 0 (QKV): cols<2048 -> bf16 qk (stride 2048); cols>=2048 -> V^T region
//   vt[((b*16+h)*64+d)*2048 + swz(t,d)], swz = chunk-XOR for conflict-free LDS.
// MODE 1: f32 row-major out.
// ---------------------------------------------------------------------------
template<int MODE>
__global__ __launch_bounds__(256) void gemm_bt(
    const bf16* __restrict__ A, const bf16* __restrict__ B,
    const float* __restrict__ bias, void* __restrict__ out0,
    bf16* __restrict__ vt, int M, int N, int K) {
  __shared__ bf16 As[128 * 32];
  __shared__ bf16 Bs[128 * 32];
  const int tid = threadIdx.x;
  const int l = tid & 63, w = tid >> 6;
  const int r = l & 15, q = l >> 4;
  const int m0 = blockIdx.y * 128, n0 = blockIdx.x * 128;
  const int wm = w >> 1, wn = w & 1;

  f32x4 acc[4][4];
#pragma unroll
  for (int i = 0; i < 4; ++i)
#pragma unroll
    for (int j = 0; j < 4; ++j) acc[i][j] = (f32x4){0.f, 0.f, 0.f, 0.f};

  const int slot0 = w * 64 + l;
  const int rowS0 = slot0 >> 2, chS0 = (slot0 & 3) * 8;
  const int slot1 = 256 + slot0;
  const int rowS1 = slot1 >> 2, chS1 = (slot1 & 3) * 8;

  const bf16* A0 = A + (size_t)(m0 + rowS0) * K + chS0;
  const bf16* A1 = A + (size_t)(m0 + rowS1) * K + chS1;
  const bf16* B0 = B + (size_t)(n0 + rowS0) * K + chS0;
  const bf16* B1 = B + (size_t)(n0 + rowS1) * K + chS1;
  char* AsD0 = (char*)As + w * 1024;
  char* AsD1 = (char*)As + 4096 + w * 1024;
  char* BsD0 = (char*)Bs + w * 1024;
  char* BsD1 = (char*)Bs + 4096 + w * 1024;

  for (int k0 = 0; k0 < K; k0 += 32) {
    __syncthreads();
    gload_lds16(A0 + k0, AsD0);
    gload_lds16(A1 + k0, AsD1);
    gload_lds16(B0 + k0, BsD0);
    gload_lds16(B1 + k0, BsD1);
    __syncthreads();

    short8 af[4], bfr[4];
#pragma unroll
    for (int mt = 0; mt < 4; ++mt)
      af[mt] = *(const short8*)(As + (wm * 64 + mt * 16 + r) * 32 + q * 8);
#pragma unroll
    for (int nt = 0; nt < 4; ++nt)
      bfr[nt] = *(const short8*)(Bs + (wn * 64 + nt * 16 + r) * 32 + q * 8);
#pragma unroll
    for (int mt = 0; mt < 4; ++mt)
#pragma unroll
      for (int nt = 0; nt < 4; ++nt)
        acc[mt][nt] = __builtin_amdgcn_mfma_f32_16x16x32_bf16(af[mt], bfr[nt], acc[mt][nt], 0, 0, 0);
  }

#pragma unroll
  for (int nt = 0; nt < 4; ++nt) {
    const int col = n0 + wn * 64 + nt * 16 + r;
    const float bv = bias[col];
#pragma unroll
    for (int mt = 0; mt < 4; ++mt) {
#pragma unroll
      for (int reg = 0; reg < 4; ++reg) {
        const int row = m0 + wm * 64 + mt * 16 + q * 4 + reg;
        const float v = acc[mt][nt][reg] + bv;
        if (MODE == 1) {
          ((float*)out0)[(size_t)row * N + col] = v;
        } else if (n0 < 2048) {
          ((bf16*)out0)[(size_t)row * QKLD + col] = __float2bfloat16(v);
        } else {
          const int f = col - 2048, h = f >> 6, d = f & 63;
          const int b = row >> 11, t = row & 2047;
          const int swz = (t & ~63) | ((((t >> 3) ^ d) & 7) << 3) | (t & 7);
          vt[((size_t)(b * 16 + h) * 64 + d) * 2048 + swz] = __float2bfloat16(v);
        }
      }
    }
  }
}

// ---------------------------------------------------------------------------
// Causal flash attention v3. Q,K from qk (stride 2048, Q prescaled), V from
// pre-transposed+swizzled vt. Block ip handles q-tiles {ip, 31-ip} (uniform
// 33 steps). V tile double-buffered via global_load_lds (1 barrier/kt).
// Row-sum via MFMA ones-trick; epilogue fuses +residual, writes bf16 pb.
// ---------------------------------------------------------------------------
__global__ __launch_bounds__(256, 4) void flash3(
    const bf16* __restrict__ qk, const bf16* __restrict__ vt,
    const float* __restrict__ x, bf16* __restrict__ pb) {
  const int ip = blockIdx.x;            // 0..15
  const int bh = blockIdx.y;            // 0..63
  const int b = bh >> 4, h = bh & 15;
  const int qlo = ip, qhi = 31 - ip;
  const int tid = threadIdx.x, l = tid & 63, w = tid >> 6;
  const int r = l & 15, quad = l >> 4;

  __shared__ bf16 VtL[2][64 * 64];      // [d][key-chunks, XOR-swizzled], 8KB each
  __shared__ bf16 Pl[4][16 * 72];       // per-wave P round-trip (C->A layout)

  const bf16* Qbase = qk + (size_t)b * TSEQ * QKLD + h * HD;
  const bf16* Kbase = Qbase + 1024;
  const bf16* Vhead = vt + (size_t)bh * 64 * 2048;

  // staging addresses: slot j*256+tid -> d=slot>>3, chunk=slot&7 (verbatim 128B rows)
  const int sl0 = tid, sl1 = 256 + tid;
  const bf16* vg0 = Vhead + (size_t)(sl0 >> 3) * 2048 + (sl0 & 7) * 8;
  const bf16* vg1 = Vhead + (size_t)(sl1 >> 3) * 2048 + (sl1 & 7) * 8;
  char* ldsb0[2] = { (char*)&VtL[0][0] + w * 1024, (char*)&VtL[1][0] + w * 1024 };
  char* ldsb1[2] = { (char*)&VtL[0][0] + 4096 + w * 1024, (char*)&VtL[1][0] + 4096 + w * 1024 };

  const bf16* qplo = Qbase + (size_t)(qlo * 64 + w * 16 + r) * QKLD + quad * 8;
  const bf16* qphi = Qbase + (size_t)(qhi * 64 + w * 16 + r) * QKLD + quad * 8;
  const short8 qlo0 = *(const short8*)qplo, qlo1 = *(const short8*)(qplo + 32);
  const short8 qhi0 = *(const short8*)qphi, qhi1 = *(const short8*)(qphi + 32);

  f32x4 o_lo[4], o_hi[4], l_lo, l_hi;
#pragma unroll
  for (int nt = 0; nt < 4; ++nt) {
    o_lo[nt] = (f32x4){0.f, 0.f, 0.f, 0.f};
    o_hi[nt] = (f32x4){0.f, 0.f, 0.f, 0.f};
  }
  l_lo = (f32x4){0.f, 0.f, 0.f, 0.f};
  l_hi = (f32x4){0.f, 0.f, 0.f, 0.f};

  short8 ones;
#pragma unroll
  for (int j = 0; j < 8; ++j) ones[j] = (short)0x3F80;  // bf16 1.0

  short8 kf0[4], kf1[4];
  const int c0 = quad ^ (r & 7);        // swizzled chunk for vf0; vf1 = c0^4

  auto step = [&](const short8& q0, const short8& q1, f32x4* o, f32x4& lacc,
                  const bf16* V, bool diag) {
    f32x4 s[4];
#pragma unroll
    for (int nt = 0; nt < 4; ++nt) {
      f32x4 a = (f32x4){0.f, 0.f, 0.f, 0.f};
      a = __builtin_amdgcn_mfma_f32_16x16x32_bf16(q0, kf0[nt], a, 0, 0, 0);
      a = __builtin_amdgcn_mfma_f32_16x16x32_bf16(q1, kf1[nt], a, 0, 0, 0);
      s[nt] = a;
    }
    bf16* PlW = &Pl[w][0];
#pragma unroll
    for (int nt = 0; nt < 4; ++nt)
#pragma unroll
      for (int reg = 0; reg < 4; ++reg) {
        float v = s[nt][reg];                       // scale pre-folded into Q
        if (diag) {
          const int kj = nt * 16 + r;
          const int qi = w * 16 + quad * 4 + reg;
          if (kj > qi) v = -__builtin_inff();
        }
        PlW[(quad * 4 + reg) * 72 + nt * 16 + r] = __float2bfloat16(exp2f(v));
      }
    const short8 pf0 = *(const short8*)(PlW + r * 72 + quad * 8);
    const short8 pf1 = *(const short8*)(PlW + r * 72 + 32 + quad * 8);
#pragma unroll
    for (int nt = 0; nt < 4; ++nt) {
      const int d = nt * 16 + r;
      const short8 vf0 = *(const short8*)(V + d * 64 + c0 * 8);
      const short8 vf1 = *(const short8*)(V + d * 64 + (c0 ^ 4) * 8);
      o[nt] = __builtin_amdgcn_mfma_f32_16x16x32_bf16(pf0, vf0, o[nt], 0, 0, 0);
      o[nt] = __builtin_amdgcn_mfma_f32_16x16x32_bf16(pf1, vf1, o[nt], 0, 0, 0);
    }
    lacc = __builtin_amdgcn_mfma_f32_16x16x32_bf16(pf0, ones, lacc, 0, 0, 0);
    lacc = __builtin_amdgcn_mfma_f32_16x16x32_bf16(pf1, ones, lacc, 0, 0, 0);
  };

  // prime pipeline: stage V tile 0 into buffer 0
  gload_lds16(vg0, ldsb0[0]);
  gload_lds16(vg1, ldsb1[0]);
  int bsel = 0;

  for (int kt = 0; kt <= qhi; ++kt) {
    // K frags for kt (shared by both q-tiles and all 4 waves; L2-resident)
#pragma unroll
    for (int nt = 0; nt < 4; ++nt) {
      const bf16* kp = Kbase + (size_t)(kt * 64 + nt * 16 + r) * QKLD + quad * 8;
      kf0[nt] = *(const short8*)kp;
      kf1[nt] = *(const short8*)(kp + 32);
    }
    __syncthreads();                    // V(kt) staged; buf[bsel^1] free
    if (kt < qhi) {
      gload_lds16(vg0 + (kt + 1) * 64, ldsb0[bsel ^ 1]);
      gload_lds16(vg1 + (kt + 1) * 64, ldsb1[bsel ^ 1]);
    }
    const bf16* V = &VtL[bsel][0];
    step(qhi0, qhi1, o_hi, l_hi, V, kt == qhi);
    if (kt <= qlo)
      step(qlo0, qlo1, o_lo, l_lo, V, kt == qlo);
    bsel ^= 1;
  }

  // epilogue: O /= l, add residual (f32 x), store bf16 pb
  auto epi = [&](int qtile, f32x4* o, f32x4& lacc) {
#pragma unroll
    for (int reg = 0; reg < 4; ++reg) {
      const float inv = 1.0f / lacc[reg];
      const int row = qtile * 64 + w * 16 + quad * 4 + reg;
      const float* xr = x + (size_t)(b * TSEQ + row) * EMB + h * HD;
      bf16* pr = pb + (size_t)(b * TSEQ + row) * EMB + h * HD;
#pragma unroll
      for (int nt = 0; nt < 4; ++nt) {
        const int d = nt * 16 + r;
        pr[d] = __float2bfloat16(o[nt][reg] * inv + xr[d]);
      }
    }
  };
  epi(qlo, o_lo, l_lo);
  epi(qhi, o_hi, l_hi);
}

// ---------------------------------------------------------------------------
// In-place LayerNorm over last dim (1024). One block per row, 256 thr x 4.
// ---------------------------------------------------------------------------
__global__ __launch_bounds__(256) void ln_kernel(float* __restrict__ out,
                                                 const float* __restrict__ gamma,
                                                 const float* __restrict__ beta) {
  const int row = blockIdx.x;
  const int tid = threadIdx.x;
  float* p = out + (size_t)row * EMB;
  float4 v = ((const float4*)p)[tid];
  float s = v.x + v.y + v.z + v.w;
  float ss = v.x * v.x + v.y * v.y + v.z * v.z + v.w * v.w;
#pragma unroll
  for (int m = 1; m < 64; m <<= 1) {
    s += __shfl_xor(s, m, 64);
    ss += __shfl_xor(ss, m, 64);
  }
  __shared__ float red[8];
  const int w = tid >> 6, l = tid & 63;
  if (l == 0) { red[w] = s; red[4 + w] = ss; }
  __syncthreads();
  s = red[0] + red[1] + red[2] + red[3];
  ss = red[4] + red[5] + red[6] + red[7];
  const float mu = s * (1.0f / EMB);
  const float var = ss * (1.0f / EMB) - mu * mu;
  const float rs = rsqrtf(var + 1e-6f);
  const float4 g = ((const float4*)gamma)[tid];
  const float4 bb = ((const float4*)beta)[tid];
  float4 o;
  o.x = (v.x - mu) * rs * g.x + bb.x;
  o.y = (v.y - mu) * rs * g.y + bb.y;
  o.z = (v.z - mu) * rs * g.z + bb.z;
  o.w = (v.w - mu) * rs * g.w + bb.w;
  ((float4*)p)[tid] = o;
}

// ---------------------------------------------------------------------------
extern "C" void kernel_launch(void* const* d_in, const int* in_sizes, int n_in,
                              void* d_out, int out_size, void* d_ws, size_t ws_size,
                              hipStream_t stream) {
  const float* x     = (const float*)d_in[0];
  const float* Wq    = (const float*)d_in[1];
  const float* bq    = (const float*)d_in[2];
  const float* Wk    = (const float*)d_in[3];
  const float* bk    = (const float*)d_in[4];
  const float* Wv    = (const float*)d_in[5];
  const float* bv    = (const float*)d_in[6];
  const float* Wp    = (const float*)d_in[7];
  const float* bp    = (const float*)d_in[8];
  const float* gamma = (const float*)d_in[9];
  const float* beta  = (const float*)d_in[10];
  float* out = (float*)d_out;

  // ws: xb 0-16M (reused as pb), wqkv 16-22M, wpb 22-24M, bqkv 24M(+12KB),
  // qk 25-57M (stride 2048), vt 57-73M ([b][h][d][T] swizzled)
  if (ws_size < (size_t)74 * 1024 * 1024) {
    printf("kernel_launch: ws_size %zu too small\n", ws_size);
    return;
  }
  char* ws = (char*)d_ws;
  bf16* xb    = (bf16*)ws;
  bf16* wqkv  = (bf16*)(ws + ((size_t)16 << 20));
  bf16* wpb   = (bf16*)(ws + ((size_t)22 << 20));
  float* bqkv = (float*)(ws + ((size_t)24 << 20));
  bf16* qkbuf = (bf16*)(ws + ((size_t)25 << 20));
  bf16* vtbuf = (bf16*)(ws + ((size_t)57 << 20));
  bf16* pbuf  = xb;  // xb dead after QKV GEMM

  fused_cast<<<12291, 256, 0, stream>>>(x, Wq, Wk, Wv, Wp, bq, bk, bv, xb, wqkv, wpb, bqkv);

  gemm_bt<0><<<dim3(24, 64), 256, 0, stream>>>(xb, wqkv, bqkv, qkbuf, vtbuf, BT, QKVN, EMB);

  flash3<<<dim3(16, 64), 256, 0, stream>>>(qkbuf, vtbuf, x, pbuf);

  gemm_bt<1><<<dim3(8, 64), 256, 0, stream>>>(pbuf, wpb, bp, out, nullptr, BT, EMB, EMB);

  ln_kernel<<<BT, 256, 0, stream>>>(out, gamma, beta);
}

// Round 4
// 325.145 us; speedup vs baseline: 1.3922x; 1.3922x over previous
//
#include <hip/hip_runtime.h>
#include <hip/hip_bf16.h>
#include <cstdint>
#include <cstdio>

#define EMB    1024
#define HEADS  16
#define HD     64
#define TSEQ   2048
#define NBATCH 4
#define BT     (NBATCH*TSEQ)   // 8192
#define QKVN   3072            // fused QKV GEMM output width
#define QKLD   2048            // Q,K buffer row stride

// log2(e) / sqrt(2048) — folded into Wq/bq at cast time
#define CSCALE (1.4426950408889634f * 0.022097086912079608f)

typedef __hip_bfloat16 bf16;
typedef __attribute__((ext_vector_type(8))) short short8;   // 8 bf16 (MFMA A/B frag)
typedef __attribute__((ext_vector_type(4))) short short4v;  // 4 bf16 = 8B
typedef __attribute__((ext_vector_type(4))) float f32x4;    // MFMA C/D frag

__device__ __forceinline__ void gload_lds16(const void* g, void* l) {
  __builtin_amdgcn_global_load_lds(
      (const __attribute__((address_space(1))) void*)g,
      (__attribute__((address_space(3))) void*)l,
      16, 0, 0);
}

// ---------------------------------------------------------------------------
// One launch: cast x -> xb, {Wq*CSCALE,Wk,Wv} -> wqkv, Wp -> wpb,
// concat {bq*CSCALE,bk,bv} -> biasqkv (f32).
// ---------------------------------------------------------------------------
__global__ void fused_cast(const float* __restrict__ x, const float* __restrict__ Wq,
                           const float* __restrict__ Wk, const float* __restrict__ Wv,
                           const float* __restrict__ Wp, const float* __restrict__ bq,
                           const float* __restrict__ bk, const float* __restrict__ bv,
                           bf16* __restrict__ xb, bf16* __restrict__ wqkv,
                           bf16* __restrict__ wpb, float* __restrict__ biasqkv) {
  const int blk = blockIdx.x;
  const int i = threadIdx.x * 4;
  if (blk >= 12288) {  // bias concat: 3 blocks x 1024 f32
    const int wsel = blk - 12288;
    const float* bsrc = wsel == 0 ? bq : (wsel == 1 ? bk : bv);
    float4 bv4 = *(const float4*)(bsrc + i);
    if (wsel == 0) { bv4.x *= CSCALE; bv4.y *= CSCALE; bv4.z *= CSCALE; bv4.w *= CSCALE; }
    *(float4*)(biasqkv + wsel * 1024 + i) = bv4;
    return;
  }
  const float* src; bf16* dst; float sc = 1.0f;
  if (blk < 8192)       { src = x  + (size_t)blk * 1024;           dst = xb   + (size_t)blk * 1024; }
  else if (blk < 9216)  { src = Wq + (size_t)(blk - 8192) * 1024;  dst = wqkv + (size_t)(blk - 8192) * 1024; sc = CSCALE; }
  else if (blk < 10240) { src = Wk + (size_t)(blk - 9216) * 1024;  dst = wqkv + ((size_t)1 << 20) + (size_t)(blk - 9216) * 1024; }
  else if (blk < 11264) { src = Wv + (size_t)(blk - 10240) * 1024; dst = wqkv + ((size_t)2 << 20) + (size_t)(blk - 10240) * 1024; }
  else                  { src = Wp + (size_t)(blk - 11264) * 1024; dst = wpb  + (size_t)(blk - 11264) * 1024; }
  float4 v = *(const float4*)(src + i);
  union { short4v v; bf16 b[4]; } u;
  u.b[0] = __float2bfloat16(v.x * sc); u.b[1] = __float2bfloat16(v.y * sc);
  u.b[2] = __float2bfloat16(v.z * sc); u.b[3] = __float2bfloat16(v.w * sc);
  *(short4v*)(dst + i) = u.v;
}

// ---------------------------------------------------------------------------
// C[M,N] = A[M,K] @ B[N,K]^T + bias.  m97 structure (128x128, BK=32,
// global_load_lds w=16, 16x16x32 MFMA, 4 waves 2x2).
// MODE 0 (QKV): cols<2048 -> bf16 qk (stride 2048); cols>=2048 -> V^T region
//   vt[((b*16+h)*64+d)*2048 + swz(t,d)], swz = chunk-XOR for conflict-free LDS.
// MODE 1: f32 row-major out.
// ---------------------------------------------------------------------------
template<int MODE>
__global__ __launch_bounds__(256) void gemm_bt(
    const bf16* __restrict__ A, const bf16* __restrict__ B,
    const float* __restrict__ bias, void* __restrict__ out0,
    bf16* __restrict__ vt, int M, int N, int K) {
  __shared__ bf16 As[128 * 32];
  __shared__ bf16 Bs[128 * 32];
  const int tid = threadIdx.x;
  const int l = tid & 63, w = tid >> 6;
  const int r = l & 15, q = l >> 4;
  const int m0 = blockIdx.y * 128, n0 = blockIdx.x * 128;
  const int wm = w >> 1, wn = w & 1;

  f32x4 acc[4][4];
#pragma unroll
  for (int i = 0; i < 4; ++i)
#pragma unroll
    for (int j = 0; j < 4; ++j) acc[i][j] = (f32x4){0.f, 0.f, 0.f, 0.f};

  const int slot0 = w * 64 + l;
  const int rowS0 = slot0 >> 2, chS0 = (slot0 & 3) * 8;
  const int slot1 = 256 + slot0;
  const int rowS1 = slot1 >> 2, chS1 = (slot1 & 3) * 8;

  const bf16* A0 = A + (size_t)(m0 + rowS0) * K + chS0;
  const bf16* A1 = A + (size_t)(m0 + rowS1) * K + chS1;
  const bf16* B0 = B + (size_t)(n0 + rowS0) * K + chS0;
  const bf16* B1 = B + (size_t)(n0 + rowS1) * K + chS1;
  char* AsD0 = (char*)As + w * 1024;
  char* AsD1 = (char*)As + 4096 + w * 1024;
  char* BsD0 = (char*)Bs + w * 1024;
  char* BsD1 = (char*)Bs + 4096 + w * 1024;

  for (int k0 = 0; k0 < K; k0 += 32) {
    __syncthreads();
    gload_lds16(A0 + k0, AsD0);
    gload_lds16(A1 + k0, AsD1);
    gload_lds16(B0 + k0, BsD0);
    gload_lds16(B1 + k0, BsD1);
    __syncthreads();

    short8 af[4], bfr[4];
#pragma unroll
    for (int mt = 0; mt < 4; ++mt)
      af[mt] = *(const short8*)(As + (wm * 64 + mt * 16 + r) * 32 + q * 8);
#pragma unroll
    for (int nt = 0; nt < 4; ++nt)
      bfr[nt] = *(const short8*)(Bs + (wn * 64 + nt * 16 + r) * 32 + q * 8);
#pragma unroll
    for (int mt = 0; mt < 4; ++mt)
#pragma unroll
      for (int nt = 0; nt < 4; ++nt)
        acc[mt][nt] = __builtin_amdgcn_mfma_f32_16x16x32_bf16(af[mt], bfr[nt], acc[mt][nt], 0, 0, 0);
  }

#pragma unroll
  for (int nt = 0; nt < 4; ++nt) {
    const int col = n0 + wn * 64 + nt * 16 + r;
    const float bv = bias[col];
#pragma unroll
    for (int mt = 0; mt < 4; ++mt) {
#pragma unroll
      for (int reg = 0; reg < 4; ++reg) {
        const int row = m0 + wm * 64 + mt * 16 + q * 4 + reg;
        const float v = acc[mt][nt][reg] + bv;
        if (MODE == 1) {
          ((float*)out0)[(size_t)row * N + col] = v;
        } else if (n0 < 2048) {
          ((bf16*)out0)[(size_t)row * QKLD + col] = __float2bfloat16(v);
        } else {
          const int f = col - 2048, h = f >> 6, d = f & 63;
          const int b = row >> 11, t = row & 2047;
          const int swz = (t & ~63) | ((((t >> 3) ^ d) & 7) << 3) | (t & 7);
          vt[((size_t)(b * 16 + h) * 64 + d) * 2048 + swz] = __float2bfloat16(v);
        }
      }
    }
  }
}

// ---------------------------------------------------------------------------
// Causal flash attention v4. Grid (bh=64, ip=8) so XCD = bh%8: all blocks
// sharing a bh's K/V run on one XCD (L2-local). Each block owns 4 q-tiles
// {31-ip, 23-ip, ip+8, ip} -> uniform 66 steps/block, K/V tile loaded once
// per block per kt (4x reuse). V double-buffered via global_load_lds; P
// round-trip LDS double-buffered to break step-to-step serialization.
// Row-sum via MFMA ones-trick; epilogue fuses +residual, writes bf16 pb.
// ---------------------------------------------------------------------------
__global__ __launch_bounds__(256, 2) void flash4(
    const bf16* __restrict__ qk, const bf16* __restrict__ vt,
    const float* __restrict__ x, bf16* __restrict__ pb) {
  const int bh = blockIdx.x;            // 0..63 -> XCD = bh%8
  const int ip = blockIdx.y;            // 0..7
  const int b = bh >> 4, h = bh & 15;
  const int qt[4] = { 31 - ip, 23 - ip, ip + 8, ip };   // descending
  const int tid = threadIdx.x, l = tid & 63, w = tid >> 6;
  const int r = l & 15, quad = l >> 4;

  __shared__ bf16 VtL[2][64 * 64];      // [d][key-chunks XOR-swizzled], 8KB each
  __shared__ bf16 Pl[2][4][16 * 72];    // double-buffered per-wave P round-trip

  const bf16* Qbase = qk + (size_t)b * TSEQ * QKLD + h * HD;
  const bf16* Kbase = Qbase + 1024;
  const bf16* Vhead = vt + (size_t)bh * 64 * 2048;

  // V staging: slot j*256+tid -> d=slot>>3, 16B chunk slot&7 (128B rows verbatim)
  const int sl0 = tid, sl1 = 256 + tid;
  const bf16* vg0 = Vhead + (size_t)(sl0 >> 3) * 2048 + (sl0 & 7) * 8;
  const bf16* vg1 = Vhead + (size_t)(sl1 >> 3) * 2048 + (sl1 & 7) * 8;
  char* ldsb0[2] = { (char*)&VtL[0][0] + w * 1024, (char*)&VtL[1][0] + w * 1024 };
  char* ldsb1[2] = { (char*)&VtL[0][0] + 4096 + w * 1024, (char*)&VtL[1][0] + 4096 + w * 1024 };

  // Q fragments for the 4 tiles
  short8 qf0[4], qf1[4];
#pragma unroll
  for (int t = 0; t < 4; ++t) {
    const bf16* qp = Qbase + (size_t)(qt[t] * 64 + w * 16 + r) * QKLD + quad * 8;
    qf0[t] = *(const short8*)qp;
    qf1[t] = *(const short8*)(qp + 32);
  }

  f32x4 o[4][4], lac[4];
#pragma unroll
  for (int t = 0; t < 4; ++t) {
    lac[t] = (f32x4){0.f, 0.f, 0.f, 0.f};
#pragma unroll
    for (int nt = 0; nt < 4; ++nt) o[t][nt] = (f32x4){0.f, 0.f, 0.f, 0.f};
  }

  short8 ones;
#pragma unroll
  for (int j = 0; j < 8; ++j) ones[j] = (short)0x3F80;  // bf16 1.0

  short8 kf0[4], kf1[4];
  const int c0 = quad ^ (r & 7);        // swizzled chunk for vf0; vf1 = c0^4

  auto step = [&](int t, const bf16* V, bf16* PlW, bool diag) {
    f32x4 s[4];
#pragma unroll
    for (int nt = 0; nt < 4; ++nt) {
      f32x4 a = (f32x4){0.f, 0.f, 0.f, 0.f};
      a = __builtin_amdgcn_mfma_f32_16x16x32_bf16(qf0[t], kf0[nt], a, 0, 0, 0);
      a = __builtin_amdgcn_mfma_f32_16x16x32_bf16(qf1[t], kf1[nt], a, 0, 0, 0);
      s[nt] = a;
    }
#pragma unroll
    for (int nt = 0; nt < 4; ++nt)
#pragma unroll
      for (int reg = 0; reg < 4; ++reg) {
        float v = s[nt][reg];                       // scale pre-folded into Q
        if (diag) {
          const int kj = nt * 16 + r;
          const int qi = w * 16 + quad * 4 + reg;
          if (kj > qi) v = -__builtin_inff();
        }
        PlW[(quad * 4 + reg) * 72 + nt * 16 + r] = __float2bfloat16(exp2f(v));
      }
    const short8 pf0 = *(const short8*)(PlW + r * 72 + quad * 8);
    const short8 pf1 = *(const short8*)(PlW + r * 72 + 32 + quad * 8);
#pragma unroll
    for (int nt = 0; nt < 4; ++nt) {
      const int d = nt * 16 + r;
      const short8 vf0 = *(const short8*)(V + d * 64 + c0 * 8);
      const short8 vf1 = *(const short8*)(V + d * 64 + (c0 ^ 4) * 8);
      o[t][nt] = __builtin_amdgcn_mfma_f32_16x16x32_bf16(pf0, vf0, o[t][nt], 0, 0, 0);
      o[t][nt] = __builtin_amdgcn_mfma_f32_16x16x32_bf16(pf1, vf1, o[t][nt], 0, 0, 0);
    }
    lac[t] = __builtin_amdgcn_mfma_f32_16x16x32_bf16(pf0, ones, lac[t], 0, 0, 0);
    lac[t] = __builtin_amdgcn_mfma_f32_16x16x32_bf16(pf1, ones, lac[t], 0, 0, 0);
  };

  // prime: stage V tile 0 into buffer 0
  gload_lds16(vg0, ldsb0[0]);
  gload_lds16(vg1, ldsb1[0]);
  int bsel = 0;

  const int ktmax = qt[0];
  for (int kt = 0; kt <= ktmax; ++kt) {
    // K frags for kt (shared by all 4 tiles; L1/L2-resident across waves)
#pragma unroll
    for (int nt = 0; nt < 4; ++nt) {
      const bf16* kp = Kbase + (size_t)(kt * 64 + nt * 16 + r) * QKLD + quad * 8;
      kf0[nt] = *(const short8*)kp;
      kf1[nt] = *(const short8*)(kp + 32);
    }
    __syncthreads();                    // V(kt) staged; buf[bsel^1] free
    if (kt < ktmax) {
      gload_lds16(vg0 + (kt + 1) * 64, ldsb0[bsel ^ 1]);
      gload_lds16(vg1 + (kt + 1) * 64, ldsb1[bsel ^ 1]);
    }
    const bf16* V = &VtL[bsel][0];
    step(0, V, &Pl[0][w][0], kt == qt[0]);
    if (kt <= qt[1]) step(1, V, &Pl[1][w][0], kt == qt[1]);
    if (kt <= qt[2]) step(2, V, &Pl[0][w][0], kt == qt[2]);
    if (kt <= qt[3]) step(3, V, &Pl[1][w][0], kt == qt[3]);
    bsel ^= 1;
  }

  // epilogue: O /= l, add residual (f32 x), store bf16 pb
#pragma unroll
  for (int t = 0; t < 4; ++t) {
#pragma unroll
    for (int reg = 0; reg < 4; ++reg) {
      const float inv = 1.0f / lac[t][reg];
      const int row = qt[t] * 64 + w * 16 + quad * 4 + reg;
      const float* xr = x + (size_t)(b * TSEQ + row) * EMB + h * HD;
      bf16* pr = pb + (size_t)(b * TSEQ + row) * EMB + h * HD;
#pragma unroll
      for (int nt = 0; nt < 4; ++nt) {
        const int d = nt * 16 + r;
        pr[d] = __float2bfloat16(o[t][nt][reg] * inv + xr[d]);
      }
    }
  }
}

// ---------------------------------------------------------------------------
// In-place LayerNorm over last dim (1024). One block per row, 256 thr x 4.
// ---------------------------------------------------------------------------
__global__ __launch_bounds__(256) void ln_kernel(float* __restrict__ out,
                                                 const float* __restrict__ gamma,
                                                 const float* __restrict__ beta) {
  const int row = blockIdx.x;
  const int tid = threadIdx.x;
  float* p = out + (size_t)row * EMB;
  float4 v = ((const float4*)p)[tid];
  float s = v.x + v.y + v.z + v.w;
  float ss = v.x * v.x + v.y * v.y + v.z * v.z + v.w * v.w;
#pragma unroll
  for (int m = 1; m < 64; m <<= 1) {
    s += __shfl_xor(s, m, 64);
    ss += __shfl_xor(ss, m, 64);
  }
  __shared__ float red[8];
  const int w = tid >> 6, l = tid & 63;
  if (l == 0) { red[w] = s; red[4 + w] = ss; }
  __syncthreads();
  s = red[0] + red[1] + red[2] + red[3];
  ss = red[4] + red[5] + red[6] + red[7];
  const float mu = s * (1.0f / EMB);
  const float var = ss * (1.0f / EMB) - mu * mu;
  const float rs = rsqrtf(var + 1e-6f);
  const float4 g = ((const float4*)gamma)[tid];
  const float4 bb = ((const float4*)beta)[tid];
  float4 o;
  o.x = (v.x - mu) * rs * g.x + bb.x;
  o.y = (v.y - mu) * rs * g.y + bb.y;
  o.z = (v.z - mu) * rs * g.z + bb.z;
  o.w = (v.w - mu) * rs * g.w + bb.w;
  ((float4*)p)[tid] = o;
}

// ---------------------------------------------------------------------------
extern "C" void kernel_launch(void* const* d_in, const int* in_sizes, int n_in,
                              void* d_out, int out_size, void* d_ws, size_t ws_size,
                              hipStream_t stream) {
  const float* x     = (const float*)d_in[0];
  const float* Wq    = (const float*)d_in[1];
  const float* bq    = (const float*)d_in[2];
  const float* Wk    = (const float*)d_in[3];
  const float* bk    = (const float*)d_in[4];
  const float* Wv    = (const float*)d_in[5];
  const float* bv    = (const float*)d_in[6];
  const float* Wp    = (const float*)d_in[7];
  const float* bp    = (const float*)d_in[8];
  const float* gamma = (const float*)d_in[9];
  const float* beta  = (const float*)d_in[10];
  float* out = (float*)d_out;

  // ws: xb 0-16M (reused as pb), wqkv 16-22M, wpb 22-24M, bqkv 24M(+12KB),
  // qk 25-57M (stride 2048), vt 57-73M ([b][h][d][T] swizzled)
  if (ws_size < (size_t)74 * 1024 * 1024) {
    printf("kernel_launch: ws_size %zu too small\n", ws_size);
    return;
  }
  char* ws = (char*)d_ws;
  bf16* xb    = (bf16*)ws;
  bf16* wqkv  = (bf16*)(ws + ((size_t)16 << 20));
  bf16* wpb   = (bf16*)(ws + ((size_t)22 << 20));
  float* bqkv = (float*)(ws + ((size_t)24 << 20));
  bf16* qkbuf = (bf16*)(ws + ((size_t)25 << 20));
  bf16* vtbuf = (bf16*)(ws + ((size_t)57 << 20));
  bf16* pbuf  = xb;  // xb dead after QKV GEMM

  fused_cast<<<12291, 256, 0, stream>>>(x, Wq, Wk, Wv, Wp, bq, bk, bv, xb, wqkv, wpb, bqkv);

  gemm_bt<0><<<dim3(24, 64), 256, 0, stream>>>(xb, wqkv, bqkv, qkbuf, vtbuf, BT, QKVN, EMB);

  flash4<<<dim3(64, 8), 256, 0, stream>>>(qkbuf, vtbuf, x, pbuf);

  gemm_bt<1><<<dim3(8, 64), 256, 0, stream>>>(pbuf, wpb, bp, out, nullptr, BT, EMB, EMB);

  ln_kernel<<<BT, 256, 0, stream>>>(out, gamma, beta);
}

// Round 5
// 308.760 us; speedup vs baseline: 1.4661x; 1.0531x over previous
//
#include <hip/hip_runtime.h>
#include <hip/hip_bf16.h>
#include <cstdint>
#include <cstdio>

#define EMB    1024
#define HEADS  16
#define HD     64
#define TSEQ   2048
#define NBATCH 4
#define BT     (NBATCH*TSEQ)   // 8192
#define QKVN   3072            // fused QKV GEMM output width
#define QKLD   2048            // Q,K buffer row stride

// log2(e) / sqrt(2048) — folded into Wq/bq at cast time
#define CSCALE (1.4426950408889634f * 0.022097086912079608f)

typedef __hip_bfloat16 bf16;
typedef __attribute__((ext_vector_type(8))) short short8;   // 8 bf16 (K=32 MFMA A/B frag)
typedef __attribute__((ext_vector_type(4))) short short4v;  // 4 bf16 (K=16 MFMA A/B frag)
typedef __attribute__((ext_vector_type(4))) float f32x4;    // MFMA C/D frag

#define MFMA32(A,B,C) __builtin_amdgcn_mfma_f32_16x16x32_bf16(A,B,C,0,0,0)
#if __has_builtin(__builtin_amdgcn_mfma_f32_16x16x16_bf16)
#define MFMA16(A,B,C) __builtin_amdgcn_mfma_f32_16x16x16_bf16(A,B,C,0,0,0)
#else
#define MFMA16(A,B,C) __builtin_amdgcn_mfma_f32_16x16x16bf16_1k(A,B,C,0,0,0)
#endif

#if __has_builtin(__builtin_amdgcn_exp2f)
#define EXP2(x) __builtin_amdgcn_exp2f(x)
#else
#define EXP2(x) exp2f(x)
#endif

template<bool B> struct BoolC { static constexpr bool value = B; };

__device__ __forceinline__ void gload_lds16(const void* g, void* l) {
  __builtin_amdgcn_global_load_lds(
      (const __attribute__((address_space(1))) void*)g,
      (__attribute__((address_space(3))) void*)l,
      16, 0, 0);
}

// pack 2 floats -> 2 bf16 (round-half-up) in one v_perm
__device__ __forceinline__ unsigned pkbf(float a, float b) {
  unsigned ua = __builtin_bit_cast(unsigned, a) + 0x8000u;
  unsigned ub = __builtin_bit_cast(unsigned, b) + 0x8000u;
  return __builtin_amdgcn_perm(ub, ua, 0x07060302u);  // {a.hi16, b.hi16}
}

// ---------------------------------------------------------------------------
// One launch: cast x -> xb, {Wq*CSCALE,Wk,Wv} -> wqkv, Wp -> wpb,
// concat {bq*CSCALE,bk,bv} -> biasqkv (f32).
// ---------------------------------------------------------------------------
__global__ void fused_cast(const float* __restrict__ x, const float* __restrict__ Wq,
                           const float* __restrict__ Wk, const float* __restrict__ Wv,
                           const float* __restrict__ Wp, const float* __restrict__ bq,
                           const float* __restrict__ bk, const float* __restrict__ bv,
                           bf16* __restrict__ xb, bf16* __restrict__ wqkv,
                           bf16* __restrict__ wpb, float* __restrict__ biasqkv) {
  const int blk = blockIdx.x;
  const int i = threadIdx.x * 4;
  if (blk >= 12288) {
    const int wsel = blk - 12288;
    const float* bsrc = wsel == 0 ? bq : (wsel == 1 ? bk : bv);
    float4 bv4 = *(const float4*)(bsrc + i);
    if (wsel == 0) { bv4.x *= CSCALE; bv4.y *= CSCALE; bv4.z *= CSCALE; bv4.w *= CSCALE; }
    *(float4*)(biasqkv + wsel * 1024 + i) = bv4;
    return;
  }
  const float* src; bf16* dst; float sc = 1.0f;
  if (blk < 8192)       { src = x  + (size_t)blk * 1024;           dst = xb   + (size_t)blk * 1024; }
  else if (blk < 9216)  { src = Wq + (size_t)(blk - 8192) * 1024;  dst = wqkv + (size_t)(blk - 8192) * 1024; sc = CSCALE; }
  else if (blk < 10240) { src = Wk + (size_t)(blk - 9216) * 1024;  dst = wqkv + ((size_t)1 << 20) + (size_t)(blk - 9216) * 1024; }
  else if (blk < 11264) { src = Wv + (size_t)(blk - 10240) * 1024; dst = wqkv + ((size_t)2 << 20) + (size_t)(blk - 10240) * 1024; }
  else                  { src = Wp + (size_t)(blk - 11264) * 1024; dst = wpb  + (size_t)(blk - 11264) * 1024; }
  float4 v = *(const float4*)(src + i);
  union { short4v v; bf16 b[4]; } u;
  u.b[0] = __float2bfloat16(v.x * sc); u.b[1] = __float2bfloat16(v.y * sc);
  u.b[2] = __float2bfloat16(v.z * sc); u.b[3] = __float2bfloat16(v.w * sc);
  *(short4v*)(dst + i) = u.v;
}

// ---------------------------------------------------------------------------
// C[M,N] = A[M,K] @ B[N,K]^T + bias.  m97 structure (128x128, BK=32,
// global_load_lds w=16, 16x16x32 MFMA, 4 waves 2x2).
// MODE 0 (QKV): cols<2048 -> bf16 qk (stride 2048); cols>=2048 -> V^T region
//   vt[((b*16+h)*64+d)*2048 + swz(t,d)], swz = chunk-XOR for conflict-free LDS.
// MODE 1: f32 row-major out.
// ---------------------------------------------------------------------------
template<int MODE>
__global__ __launch_bounds__(256) void gemm_bt(
    const bf16* __restrict__ A, const bf16* __restrict__ B,
    const float* __restrict__ bias, void* __restrict__ out0,
    bf16* __restrict__ vt, int M, int N, int K) {
  __shared__ bf16 As[128 * 32];
  __shared__ bf16 Bs[128 * 32];
  const int tid = threadIdx.x;
  const int l = tid & 63, w = tid >> 6;
  const int r = l & 15, q = l >> 4;
  const int m0 = blockIdx.y * 128, n0 = blockIdx.x * 128;
  const int wm = w >> 1, wn = w & 1;

  f32x4 acc[4][4];
#pragma unroll
  for (int i = 0; i < 4; ++i)
#pragma unroll
    for (int j = 0; j < 4; ++j) acc[i][j] = (f32x4){0.f, 0.f, 0.f, 0.f};

  const int slot0 = w * 64 + l;
  const int rowS0 = slot0 >> 2, chS0 = (slot0 & 3) * 8;
  const int slot1 = 256 + slot0;
  const int rowS1 = slot1 >> 2, chS1 = (slot1 & 3) * 8;

  const bf16* A0 = A + (size_t)(m0 + rowS0) * K + chS0;
  const bf16* A1 = A + (size_t)(m0 + rowS1) * K + chS1;
  const bf16* B0 = B + (size_t)(n0 + rowS0) * K + chS0;
  const bf16* B1 = B + (size_t)(n0 + rowS1) * K + chS1;
  char* AsD0 = (char*)As + w * 1024;
  char* AsD1 = (char*)As + 4096 + w * 1024;
  char* BsD0 = (char*)Bs + w * 1024;
  char* BsD1 = (char*)Bs + 4096 + w * 1024;

  for (int k0 = 0; k0 < K; k0 += 32) {
    __syncthreads();
    gload_lds16(A0 + k0, AsD0);
    gload_lds16(A1 + k0, AsD1);
    gload_lds16(B0 + k0, BsD0);
    gload_lds16(B1 + k0, BsD1);
    __syncthreads();

    short8 af[4], bfr[4];
#pragma unroll
    for (int mt = 0; mt < 4; ++mt)
      af[mt] = *(const short8*)(As + (wm * 64 + mt * 16 + r) * 32 + q * 8);
#pragma unroll
    for (int nt = 0; nt < 4; ++nt)
      bfr[nt] = *(const short8*)(Bs + (wn * 64 + nt * 16 + r) * 32 + q * 8);
#pragma unroll
    for (int mt = 0; mt < 4; ++mt)
#pragma unroll
      for (int nt = 0; nt < 4; ++nt)
        acc[mt][nt] = MFMA32(af[mt], bfr[nt], acc[mt][nt]);
  }

#pragma unroll
  for (int nt = 0; nt < 4; ++nt) {
    const int col = n0 + wn * 64 + nt * 16 + r;
    const float bv = bias[col];
#pragma unroll
    for (int mt = 0; mt < 4; ++mt) {
#pragma unroll
      for (int reg = 0; reg < 4; ++reg) {
        const int row = m0 + wm * 64 + mt * 16 + q * 4 + reg;
        const float v = acc[mt][nt][reg] + bv;
        if (MODE == 1) {
          ((float*)out0)[(size_t)row * N + col] = v;
        } else if (n0 < 2048) {
          ((bf16*)out0)[(size_t)row * QKLD + col] = __float2bfloat16(v);
        } else {
          const int f = col - 2048, h = f >> 6, d = f & 63;
          const int b = row >> 11, t = row & 2047;
          const int swz = (t & ~63) | ((((t >> 3) ^ d) & 7) << 3) | (t & 7);
          vt[((size_t)(b * 16 + h) * 64 + d) * 2048 + swz] = __float2bfloat16(v);
        }
      }
    }
  }
}

// ---------------------------------------------------------------------------
// Causal flash attention v5: in-register P via S-transpose trick.
// S^T = K·Q^T (swap MFMA operands): S^T C-layout rows (quad*4+reg) == A-frag
// k-indices of 16x16x16 MFMA, so exp2(S^T) packs directly into PV A-frags —
// no LDS round-trip. Grid (bh=64, ip=8), XCD = bh%8 (L2-local); 4 q-tiles
// per block; V tile double-buffered in LDS via global_load_lds, V-frags
// (ds_read_b64) hoisted once per kt and shared by all 4 tile-steps.
// Row-sum via MFMA ones-trick; epilogue fuses +residual, writes bf16 pb.
// ---------------------------------------------------------------------------
__global__ __launch_bounds__(256, 2) void flash5(
    const bf16* __restrict__ qk, const bf16* __restrict__ vt,
    const float* __restrict__ x, bf16* __restrict__ pb) {
  const int bh = blockIdx.x;            // 0..63 -> XCD = bh%8
  const int ip = blockIdx.y;            // 0..7
  const int b = bh >> 4, h = bh & 15;
  const int qt[4] = { 31 - ip, 23 - ip, ip + 8, ip };   // descending
  const int tid = threadIdx.x, l = tid & 63, w = tid >> 6;
  const int r = l & 15, quad = l >> 4;

  __shared__ bf16 VtL[2][64 * 64];      // [d][key-chunks XOR-swizzled], 8KB each

  const bf16* Qbase = qk + (size_t)b * TSEQ * QKLD + h * HD;
  const bf16* Kbase = Qbase + 1024;
  const bf16* Vhead = vt + (size_t)bh * 64 * 2048;

  // V staging: slot j*256+tid -> d=slot>>3, 16B chunk slot&7 (128B rows verbatim)
  const int sl0 = tid, sl1 = 256 + tid;
  const bf16* vg0 = Vhead + (size_t)(sl0 >> 3) * 2048 + (sl0 & 7) * 8;
  const bf16* vg1 = Vhead + (size_t)(sl1 >> 3) * 2048 + (sl1 & 7) * 8;
  char* ldsb0[2] = { (char*)&VtL[0][0] + w * 1024, (char*)&VtL[1][0] + w * 1024 };
  char* ldsb1[2] = { (char*)&VtL[0][0] + 4096 + w * 1024, (char*)&VtL[1][0] + 4096 + w * 1024 };

  // Q fragments (B-operand of S^T: n=lane&15=qrow, k=quad*8+j) — same loads as ever
  short8 qf0[4], qf1[4];
#pragma unroll
  for (int t = 0; t < 4; ++t) {
    const bf16* qp = Qbase + (size_t)(qt[t] * 64 + w * 16 + r) * QKLD + quad * 8;
    qf0[t] = *(const short8*)qp;
    qf1[t] = *(const short8*)(qp + 32);
  }

  f32x4 o[4][4], lac[4];
#pragma unroll
  for (int t = 0; t < 4; ++t) {
    lac[t] = (f32x4){0.f, 0.f, 0.f, 0.f};
#pragma unroll
    for (int nt = 0; nt < 4; ++nt) o[t][nt] = (f32x4){0.f, 0.f, 0.f, 0.f};
  }

  short4v ones4;
#pragma unroll
  for (int j = 0; j < 4; ++j) ones4[j] = (short)0x3F80;  // bf16 1.0

  short8 kf0[4], kf1[4];
  short4v vf[4][4];

  // prime: stage V tile 0 into buffer 0
  gload_lds16(vg0, ldsb0[0]);
  gload_lds16(vg1, ldsb1[0]);
  int bsel = 0;

  const int ktmax = qt[0];
  const int qrow_l = w * 16 + r;        // local q row within tile
  for (int kt = 0; kt <= ktmax; ++kt) {
    // K frags (A-operand of S^T: m=lane&15=key, k=quad*8+j) — same loads as ever
#pragma unroll
    for (int g = 0; g < 4; ++g) {
      const bf16* kp = Kbase + (size_t)(kt * 64 + g * 16 + r) * QKLD + quad * 8;
      kf0[g] = *(const short8*)kp;
      kf1[g] = *(const short8*)(kp + 32);
    }
    __syncthreads();                    // V(kt) staged; buf[bsel^1] free
    if (kt < ktmax) {
      gload_lds16(vg0 + (kt + 1) * 64, ldsb0[bsel ^ 1]);
      gload_lds16(vg1 + (kt + 1) * 64, ldsb1[bsel ^ 1]);
    }
    // V B-frags for 16x16x16 (k=key=quad*4+j, n=d=lane&15), swizzle-aware b64
    {
      const bf16* V = &VtL[bsel][0];
#pragma unroll
      for (int nt = 0; nt < 4; ++nt)
#pragma unroll
        for (int g = 0; g < 4; ++g)
          vf[nt][g] = *(const short4v*)(V + (nt * 16 + r) * 64 +
                                        (((g * 2 + (quad >> 1)) ^ (r & 7)) * 8) + (quad & 1) * 4);
    }

    auto tilestep = [&](int t, auto diagc) {
      constexpr bool D = decltype(diagc)::value;
      f32x4 s[4];
#pragma unroll
      for (int g = 0; g < 4; ++g) {
        f32x4 a = (f32x4){0.f, 0.f, 0.f, 0.f};
        a = MFMA32(kf0[g], qf0[t], a);  // A=K, B=Q -> S^T[key][q]
        a = MFMA32(kf1[g], qf1[t], a);
        s[g] = a;
      }
      short4v pA[4];
#pragma unroll
      for (int g = 0; g < 4; ++g) {
        float p[4];
#pragma unroll
        for (int reg = 0; reg < 4; ++reg) {
          float e = EXP2(s[g][reg]);    // scale pre-folded into Q
          if (D) {
            const int kj = g * 16 + quad * 4 + reg;   // key local (kt==qt)
            if (kj > qrow_l) e = 0.f;
          }
          p[reg] = e;
        }
        union { short4v v; unsigned u[2]; } pu;
        pu.u[0] = pkbf(p[0], p[1]);
        pu.u[1] = pkbf(p[2], p[3]);
        pA[g] = pu.v;
      }
#pragma unroll
      for (int nt = 0; nt < 4; ++nt)
#pragma unroll
        for (int g = 0; g < 4; ++g)
          o[t][nt] = MFMA16(pA[g], vf[nt][g], o[t][nt]);
#pragma unroll
      for (int g = 0; g < 4; ++g)
        lac[t] = MFMA16(pA[g], ones4, lac[t]);
    };

    if (kt == qt[0]) tilestep(0, BoolC<true>{}); else tilestep(0, BoolC<false>{});
    if (kt <= qt[1]) { if (kt == qt[1]) tilestep(1, BoolC<true>{}); else tilestep(1, BoolC<false>{}); }
    if (kt <= qt[2]) { if (kt == qt[2]) tilestep(2, BoolC<true>{}); else tilestep(2, BoolC<false>{}); }
    if (kt <= qt[3]) { if (kt == qt[3]) tilestep(3, BoolC<true>{}); else tilestep(3, BoolC<false>{}); }
    bsel ^= 1;
  }

  // epilogue: O /= l, add residual (f32 x), store bf16 pb
#pragma unroll
  for (int t = 0; t < 4; ++t) {
#pragma unroll
    for (int reg = 0; reg < 4; ++reg) {
      const float inv = 1.0f / lac[t][reg];
      const int row = qt[t] * 64 + w * 16 + quad * 4 + reg;
      const float* xr = x + (size_t)(b * TSEQ + row) * EMB + h * HD;
      bf16* pr = pb + (size_t)(b * TSEQ + row) * EMB + h * HD;
#pragma unroll
      for (int nt = 0; nt < 4; ++nt) {
        const int d = nt * 16 + r;
        pr[d] = __float2bfloat16(o[t][nt][reg] * inv + xr[d]);
      }
    }
  }
}

// ---------------------------------------------------------------------------
// In-place LayerNorm over last dim (1024). One block per row, 256 thr x 4.
// ---------------------------------------------------------------------------
__global__ __launch_bounds__(256) void ln_kernel(float* __restrict__ out,
                                                 const float* __restrict__ gamma,
                                                 const float* __restrict__ beta) {
  const int row = blockIdx.x;
  const int tid = threadIdx.x;
  float* p = out + (size_t)row * EMB;
  float4 v = ((const float4*)p)[tid];
  float s = v.x + v.y + v.z + v.w;
  float ss = v.x * v.x + v.y * v.y + v.z * v.z + v.w * v.w;
#pragma unroll
  for (int m = 1; m < 64; m <<= 1) {
    s += __shfl_xor(s, m, 64);
    ss += __shfl_xor(ss, m, 64);
  }
  __shared__ float red[8];
  const int w = tid >> 6, l = tid & 63;
  if (l == 0) { red[w] = s; red[4 + w] = ss; }
  __syncthreads();
  s = red[0] + red[1] + red[2] + red[3];
  ss = red[4] + red[5] + red[6] + red[7];
  const float mu = s * (1.0f / EMB);
  const float var = ss * (1.0f / EMB) - mu * mu;
  const float rs = rsqrtf(var + 1e-6f);
  const float4 g = ((const float4*)gamma)[tid];
  const float4 bb = ((const float4*)beta)[tid];
  float4 o;
  o.x = (v.x - mu) * rs * g.x + bb.x;
  o.y = (v.y - mu) * rs * g.y + bb.y;
  o.z = (v.z - mu) * rs * g.z + bb.z;
  o.w = (v.w - mu) * rs * g.w + bb.w;
  ((float4*)p)[tid] = o;
}

// ---------------------------------------------------------------------------
extern "C" void kernel_launch(void* const* d_in, const int* in_sizes, int n_in,
                              void* d_out, int out_size, void* d_ws, size_t ws_size,
                              hipStream_t stream) {
  const float* x     = (const float*)d_in[0];
  const float* Wq    = (const float*)d_in[1];
  const float* bq    = (const float*)d_in[2];
  const float* Wk    = (const float*)d_in[3];
  const float* bk    = (const float*)d_in[4];
  const float* Wv    = (const float*)d_in[5];
  const float* bv    = (const float*)d_in[6];
  const float* Wp    = (const float*)d_in[7];
  const float* bp    = (const float*)d_in[8];
  const float* gamma = (const float*)d_in[9];
  const float* beta  = (const float*)d_in[10];
  float* out = (float*)d_out;

  // ws: xb 0-16M (reused as pb), wqkv 16-22M, wpb 22-24M, bqkv 24M(+12KB),
  // qk 25-57M (stride 2048), vt 57-73M ([b][h][d][T] swizzled)
  if (ws_size < (size_t)74 * 1024 * 1024) {
    printf("kernel_launch: ws_size %zu too small\n", ws_size);
    return;
  }
  char* ws = (char*)d_ws;
  bf16* xb    = (bf16*)ws;
  bf16* wqkv  = (bf16*)(ws + ((size_t)16 << 20));
  bf16* wpb   = (bf16*)(ws + ((size_t)22 << 20));
  float* bqkv = (float*)(ws + ((size_t)24 << 20));
  bf16* qkbuf = (bf16*)(ws + ((size_t)25 << 20));
  bf16* vtbuf = (bf16*)(ws + ((size_t)57 << 20));
  bf16* pbuf  = xb;  // xb dead after QKV GEMM

  fused_cast<<<12291, 256, 0, stream>>>(x, Wq, Wk, Wv, Wp, bq, bk, bv, xb, wqkv, wpb, bqkv);

  gemm_bt<0><<<dim3(24, 64), 256, 0, stream>>>(xb, wqkv, bqkv, qkbuf, vtbuf, BT, QKVN, EMB);

  flash5<<<dim3(64, 8), 256, 0, stream>>>(qkbuf, vtbuf, x, pbuf);

  gemm_bt<1><<<dim3(8, 64), 256, 0, stream>>>(pbuf, wpb, bp, out, nullptr, BT, EMB, EMB);

  ln_kernel<<<BT, 256, 0, stream>>>(out, gamma, beta);
}